// Round 8
// baseline (273.877 us; speedup 1.0000x reference)
//
#include <hip/hip_runtime.h>
#include <hip/hip_fp16.h>
#include <cmath>

#define BATCH 16
#define NID   15
#define NSEG  240
#define HW    262144          // 512*512
#define HEADB 65536
#define NSPL  8               // pixel splits per seg-chunk in hist
#define NCHK  4               // seg chunks (4+4+4+3)
#define PREBLK 256            // pre blocks PER DISPATCH (2 dispatches of 8 batches)
#define PSTRIDE 112           // floats per pre-block partial record

// compact key space for d = exp(-arg) in [0,1]
#define KFINEBASE 30208       // 0x3B800000 >> 15
#define KOVF 119
#define KTOT 2424             // 119 + 2305

typedef float v2f __attribute__((ext_vector_type(2)));

__device__ __forceinline__ int keyof(float d) {
  unsigned b = __float_as_uint(d);
  return (b >= 0x3B800000u) ? (int)((b >> 15) - KFINEBASE + KOVF) : (int)(b >> 23);
}
__device__ __forceinline__ void boundsof(int k, float* lo, float* hi) {
  if (k >= KOVF) {
    unsigned u = (unsigned)(k - KOVF + KFINEBASE) << 15;
    *lo = __uint_as_float(u);
    *hi = __uint_as_float(u + 32768u);
  } else {
    *lo = __uint_as_float((unsigned)k << 23);
    *hi = __uint_as_float((unsigned)(k + 1) << 23);
  }
}

__device__ __forceinline__ float fast_tanh(float x) {
  float e = __expf(2.0f * x);
  return 1.0f - 2.0f / (e + 1.0f);
}
__device__ __forceinline__ float fast_sigmoid(float x) {
  return 1.0f / (1.0f + __expf(-x));
}

struct Params { float cx, cy, e0, e1, var, valid, cnt; };
__device__ __forceinline__ Params calc_params(const float* __restrict__ st) {
  Params p;
  float cnt = st[0];
  float safe = fmaxf(cnt, 1.0f);
  p.cx = st[1] / safe;
  p.cy = st[2] / safe;
  float m0 = st[3] / safe, m1 = st[4] / safe;
  float v0 = st[5] - 2.0f * m0 * (m0 * safe) + m0 * m0 * cnt;
  float v1 = st[6] - 2.0f * m1 * (m1 * safe) + m1 * m1 * cnt;
  p.var = (v0 + v1) / (2.0f * safe);
  p.e0 = expf(10.0f * m0);
  p.e1 = expf(10.0f * m1);
  p.valid = (cnt > 0.f) ? 1.f : 0.f;
  p.cnt = cnt;
  return p;
}

// ---------------- pre: register stats (R7 structure). Split into TWO dispatches of
// 8 batches each so each dispatch is ~36-45us -> hist/lovasz surface in top-5 counters.
// __launch_bounds__(256,2) is MANDATORY (R4/R6: without it VGPR caps at 64 -> spill).
__global__ void __launch_bounds__(256, 2)
pre_kernel(const float* __restrict__ pred, const int* __restrict__ inst,
           const int* __restrict__ lab, float* __restrict__ blockpart,
           unsigned* __restrict__ exyh, unsigned* __restrict__ tb8,
           unsigned* __restrict__ sd8, int b0) {
  __shared__ float ws[4][NID * 7 + 1];
  int tid = threadIdx.x;
  int w = tid >> 6, lane = tid & 63;
  int gid = blockIdx.x;
  int b = (gid >> 5) + b0, c = gid & 31;  // 32 blocks per batch, 8192 px per block
  const float* pb = pred + (size_t)b * 5 * HW;
  const int4* ip = (const int4*)(inst + (size_t)b * HW);
  const int4* lp = (const int4*)(lab + (size_t)b * HW);
  size_t bq = (size_t)b * (HW / 4);
  // acc pairs: [0]=(cnt,ex) [1]=(ey,p2) [2]=(p3,q2) [3]=(q3,-)
  v2f acc[NID][4];
#pragma unroll
  for (int id = 0; id < NID; ++id)
#pragma unroll
    for (int s = 0; s < 4; ++s) acc[id][s] = (v2f)(0.f);
  float bgacc = 0.f;
  // prologue prefetch of iteration 0
  int g0 = c * 2048 + tid;
  float4 A0 = ((const float4*)pb)[g0];
  float4 A1 = ((const float4*)(pb + HW))[g0];
  float4 A2 = ((const float4*)(pb + 2 * HW))[g0];
  float4 A3 = ((const float4*)(pb + 3 * HW))[g0];
  float4 A4 = ((const float4*)(pb + 4 * HW))[g0];
  int4 T4 = ip[g0];
  int4 L4 = lp[g0];
#pragma unroll 1
  for (int it = 0; it < 8; ++it) {
    int g = c * 2048 + it * 256 + tid;
    float4 v0 = A0, v1 = A1, v2 = A2, v3 = A3, v4 = A4;
    int4 t4 = T4, l4 = L4;
    if (it < 7) {
      int gn = g + 256;
      A0 = ((const float4*)pb)[gn];
      A1 = ((const float4*)(pb + HW))[gn];
      A2 = ((const float4*)(pb + 2 * HW))[gn];
      A3 = ((const float4*)(pb + 3 * HW))[gn];
      A4 = ((const float4*)(pb + 4 * HW))[gn];
      T4 = ip[gn];
      L4 = lp[gn];
    }
    float p0a[4] = {v0.x, v0.y, v0.z, v0.w};
    float p1a[4] = {v1.x, v1.y, v1.z, v1.w};
    float p2a[4] = {v2.x, v2.y, v2.z, v2.w};
    float p3a[4] = {v3.x, v3.y, v3.z, v3.w};
    float p4a[4] = {v4.x, v4.y, v4.z, v4.w};
    int ta[4] = {t4.x, t4.y, t4.z, t4.w};
    int la[4] = {l4.x, l4.y, l4.z, l4.w};
    unsigned eo[4], tpack = 0, spack = 0;
    int px0 = g * 4;
#pragma unroll
    for (int k = 0; k < 4; ++k) {
      int px = px0 + k;
      float xm = (float)(px & 511) * (1.0f / 511.0f);
      float ym = (float)(px >> 9) * (1.0f / 511.0f);
      float ex = fast_tanh(p0a[k]) + xm;
      float ey = fast_tanh(p1a[k]) + ym;
      float sd = fast_sigmoid(p4a[k]);
      __half2 h = __floats2half2_rn(ex, ey);
      eo[k] = *reinterpret_cast<unsigned*>(&h);
      int t = ta[k];
      tpack |= ((unsigned)(t & 255)) << (8 * k);
      unsigned sq = (unsigned)(sd * 255.0f + 0.5f);
      spack |= (sq & 255u) << (8 * k);
      float p2 = p2a[k], p3 = p3a[k];
      v2f P01; P01.x = 1.0f; P01.y = ex;
      v2f P23; P23.x = ey;   P23.y = p2;
      v2f P45; P45.x = p3;   P45.y = p2 * p2;
      v2f P67; P67.x = p3 * p3; P67.y = 0.f;
#pragma unroll
      for (int id = 0; id < NID; ++id) {
        float pr = (t == id + 1) ? 1.0f : 0.0f;
        v2f prv; prv.x = pr; prv.y = pr;
        acc[id][0] = prv * P01 + acc[id][0];
        acc[id][1] = prv * P23 + acc[id][1];
        acc[id][2] = prv * P45 + acc[id][2];
        acc[id][3] = prv * P67 + acc[id][3];
      }
      if (la[k] == 0) bgacc += sd * sd;
    }
    ((uint4*)exyh)[bq + g] = make_uint4(eo[0], eo[1], eo[2], eo[3]);
    tb8[bq + g] = tpack;
    sd8[bq + g] = spack;
  }
  // wave shfl reduction of 105 accumulators + bg
#pragma unroll
  for (int id = 0; id < NID; ++id) {
    float vals7[7] = {acc[id][0].x, acc[id][0].y, acc[id][1].x, acc[id][1].y,
                      acc[id][2].x, acc[id][2].y, acc[id][3].x};
#pragma unroll
    for (int s = 0; s < 7; ++s) {
      float v = vals7[s];
      for (int off = 32; off > 0; off >>= 1) v += __shfl_down(v, off, 64);
      if (lane == 0) ws[w][id * 7 + s] = v;
    }
  }
  for (int off = 32; off > 0; off >>= 1) bgacc += __shfl_down(bgacc, off, 64);
  if (lane == 0) ws[w][NID * 7] = bgacc;
  __syncthreads();
  float* bp = blockpart + (size_t)(b * 32 + c) * PSTRIDE;
  for (int i = tid; i < NID * 7 + 1; i += 256)
    bp[i] = ws[0][i] + ws[1][i] + ws[2][i] + ws[3][i];
}

// ---------------- reduce pre partials (32 blocks/batch) -> stats, seedbg ----------------
__global__ void reduce_kernel(const float* __restrict__ blockpart, float* __restrict__ stats,
                              float* __restrict__ seedbg) {
  int s = blockIdx.x;       // 0..105
  int b = blockIdx.y;
  int tid = threadIdx.x;    // 64
  float v = (tid < 32) ? blockpart[(size_t)(b * 32 + tid) * PSTRIDE + s] : 0.f;
  for (int off = 32; off > 0; off >>= 1) v += __shfl_down(v, off, 64);
  if (tid == 0) {
    if (s < NID * 7) {
      int id = s / 7, st = s % 7;
      stats[(b * NID + id) * 8 + st] = v;
    } else {
      seedbg[b] = v;
    }
  }
}

// ---------------- hist: 4 segments per block, packed pos|neg LDS histograms ----------------
__global__ void __launch_bounds__(512)
hist_kernel(const unsigned* __restrict__ exyh, const unsigned* __restrict__ tb8,
            const unsigned* __restrict__ sd8, const float* __restrict__ stats,
            unsigned* __restrict__ partPN, float* __restrict__ seedi) {
  int split = blockIdx.x;       // 0..7
  int chunk = blockIdx.y;       // 0..3
  int b = blockIdx.z;           // 0..15
  int seg0 = chunk * 4;         // first local seg id in chunk (global id seg0..seg0+3, <15)
  __shared__ unsigned lhist[4 * KTOT];
  __shared__ float prm[4][5];   // cx, cy, e0, e1, valid
  int tid = threadIdx.x;
  if (tid < 4) {
    int gs = seg0 + tid;
    if (gs < NID) {
      Params pp = calc_params(stats + (size_t)(b * NID + gs) * 8);
      prm[tid][0] = pp.cx; prm[tid][1] = pp.cy; prm[tid][2] = pp.e0; prm[tid][3] = pp.e1;
      prm[tid][4] = pp.valid;
    } else {
      prm[tid][4] = 0.f;
    }
  }
  for (int k = tid; k < 4 * KTOT; k += 512) lhist[k] = 0u;
  __syncthreads();
  float cxr[4], cyr[4], e0r[4], e1r[4];
  bool vr[4];
#pragma unroll
  for (int n = 0; n < 4; ++n) {
    cxr[n] = prm[n][0]; cyr[n] = prm[n][1]; e0r[n] = prm[n][2]; e1r[n] = prm[n][3];
    vr[n] = (prm[n][4] != 0.f);
  }
  const uint4* ev = (const uint4*)exyh + (size_t)b * (HW / 4);
  const unsigned* tv = tb8 + (size_t)b * (HW / 4);
  const unsigned* sv = sd8 + (size_t)b * (HW / 4);
  int lane = tid & 63;
  int wid = tid >> 6;               // 8 waves
  int swl = (lane * 21) & 63;       // decorrelate bucket keys within a wave
  float sacc[4] = {0.f, 0.f, 0.f, 0.f};
  // groups: 65536/batch; per split 8192; per block 16 iters of 512
  int g = split * 8192 + wid * 64 + swl;
  uint4 ee = ev[g];
  unsigned tp = tv[g];
  unsigned sp = sv[g];
  for (int it = 0; it < 16; ++it) {
    uint4 ne; unsigned ntp, nsp;
    int ng = g + 512;
    if (it < 15) { ne = ev[ng]; ntp = tv[ng]; nsp = sv[ng]; }
    unsigned ew[4] = {ee.x, ee.y, ee.z, ee.w};
#pragma unroll
    for (int k = 0; k < 4; ++k) {
      unsigned u = ew[k];
      __half2 h = *reinterpret_cast<__half2*>(&u);
      float2 e = __half22float2(h);
      int t = (int)((tp >> (8 * k)) & 255u);
#pragma unroll
      for (int n = 0; n < 4; ++n) {
        if (!vr[n]) continue;
        float dx = e.x - cxr[n];
        float dy = e.y - cyr[n];
        float d = __expf(-(e0r[n] * dx * dx + e1r[n] * dy * dy));
        int key = keyof(d);
        bool pos = (t == seg0 + n + 1);
        atomicAdd(&lhist[n * KTOT + key], pos ? 65536u : 1u);
        if (pos) {
          float sd = (float)((sp >> (8 * k)) & 255u) * (1.0f / 255.0f);
          float df = sd - d;
          sacc[n] += df * df;
        }
      }
    }
    if (it < 15) { ee = ne; tp = ntp; sp = nsp; g = ng; }
  }
#pragma unroll
  for (int n = 0; n < 4; ++n) {
    float v = sacc[n];
    for (int off = 32; off > 0; off >>= 1) v += __shfl_down(v, off, 64);
    if (lane == 0 && v != 0.f) atomicAdd(&seedi[b * NID + seg0 + n], v);
  }
  __syncthreads();
#pragma unroll
  for (int n = 0; n < 4; ++n) {
    int gs = seg0 + n;
    if (gs >= NID) break;
    size_t base = ((size_t)(b * NID + gs) * NSPL + split) * KTOT;
    for (int k = tid; k < KTOT; k += 512) partPN[base + k] = lhist[n * KTOT + k];
  }
}

// ---------------- lovasz: barrier-light wave-shfl scans ----------------
__global__ void __launch_bounds__(1024)
lovasz_kernel(const unsigned* __restrict__ partPN, const float* __restrict__ stats,
              float* __restrict__ instAcc) {
  __shared__ int histP[KTOT];
  __shared__ int histN[KTOT];
  __shared__ int PreP[KTOT + 1];
  __shared__ int PreN[KTOT + 1];
  __shared__ int wtP[16];
  __shared__ int wtN[16];
  __shared__ float wred[16];
  __shared__ float prm[2];
  int seg = blockIdx.x;
  int tid = threadIdx.x;
  int lane = tid & 63, w = tid >> 6;
  if (tid == 0) {
    Params pp = calc_params(stats + (size_t)seg * 8);
    prm[0] = pp.valid;
    prm[1] = pp.cnt;
  }
  __syncthreads();
  if (prm[0] == 0.f) {
    if (tid == 0) instAcc[seg] = 0.f;
    return;
  }
  int P = (int)prm[1];
  int Nn = HW - P;
  for (int k = tid; k < KTOT; k += 1024) {
    int sp = 0, sn = 0;
#pragma unroll
    for (int s = 0; s < NSPL; ++s) {
      unsigned v = partPN[((size_t)seg * NSPL + s) * KTOT + k];
      sp += (int)(v >> 16);
      sn += (int)(v & 0xFFFFu);
    }
    histP[k] = sp;
    histN[k] = sn;
  }
  __syncthreads();
  // --- prefix sums of histP/histN via wave shfl scans ---
  {
    int base = tid * 3;
    int p0 = (base < KTOT) ? histP[base] : 0;
    int p1 = (base + 1 < KTOT) ? histP[base + 1] : 0;
    int p2 = (base + 2 < KTOT) ? histP[base + 2] : 0;
    int n0 = (base < KTOT) ? histN[base] : 0;
    int n1 = (base + 1 < KTOT) ? histN[base + 1] : 0;
    int n2 = (base + 2 < KTOT) ? histN[base + 2] : 0;
    int ap = p0 + p1 + p2, an = n0 + n1 + n2;
    int sip = ap, sin_ = an;          // wave-inclusive scans
    for (int off = 1; off < 64; off <<= 1) {
      int up = __shfl_up(sip, off, 64);
      int un = __shfl_up(sin_, off, 64);
      if (lane >= off) { sip += up; sin_ += un; }
    }
    if (lane == 63) { wtP[w] = sip; wtN[w] = sin_; }
    __syncthreads();
    int woffP = 0, woffN = 0, totP = 0, totN = 0;
#pragma unroll
    for (int j = 0; j < 16; ++j) {
      int tp = wtP[j], tn = wtN[j];
      totP += tp; totN += tn;
      if (j < w) { woffP += tp; woffN += tn; }
    }
    int exP = woffP + sip - ap;       // exclusive prefix over all earlier threads
    int exN = woffN + sin_ - an;
    if (base < KTOT) {
      PreP[base] = exP;
      PreN[base] = exN;
    }
    if (base + 1 < KTOT) {
      PreP[base + 1] = exP + p0;
      PreN[base + 1] = exN + n0;
    }
    if (base + 2 < KTOT) {
      PreP[base + 2] = exP + p0 + p1;
      PreN[base + 2] = exN + n0 + n1;
    }
    if (tid == 0) {
      PreP[KTOT] = totP;
      PreN[KTOT] = totN;
    }
    __syncthreads();
  }
  float acc = 0.f;
  for (int k = tid; k < KTOT; k += 1024) {
    int hp = histP[k], hn = histN[k];
    if ((hp | hn) == 0) continue;
    float lo, hi;
    boundsof(k, &lo, &hi);
    float m = 0.5f * (lo + hi);
    m = fminf(m, __uint_as_float(0x3F7FFFFFu));
    float tv = 1.0f - m;
    int j = keyof(tv);
    float jlo, jhi;
    boundsof(j, &jlo, &jhi);
    float den = jhi - jlo;
    float fr = (den > 0.f) ? (tv - jlo) / den : 0.5f;
    fr = fminf(fmaxf(fr, 0.f), 1.f);
    if (hp) {
      float q = (float)(Nn - PreN[j + 1]) + (1.0f - fr) * (float)histN[j];
      float a = 2.0f - 2.0f * m;
      acc += (float)hp * a / ((float)P + q);
    }
    if (hn) {
      float p = (float)PreP[j] + fr * (float)histP[j];
      int R = Nn - PreN[k + 1];
      float u0 = 1.0f / (float)(P + R);
      float u1 = 1.0f / (float)(P + R + hn);
      acc += (2.0f * m) * ((float)P - p) * (u0 - u1);
    }
  }
  // block reduction: wave shfl + 16 partials + wave-0 finish
  for (int off = 32; off > 0; off >>= 1) acc += __shfl_down(acc, off, 64);
  if (lane == 0) wred[w] = acc;
  __syncthreads();
  if (w == 0) {
    float v = (lane < 16) ? wred[lane] : 0.f;
    for (int off = 8; off > 0; off >>= 1) v += __shfl_down(v, off, 64);
    if (lane == 0) instAcc[seg] = v;
  }
}

// ---------------- final combine ----------------
__global__ void final_kernel(const float* __restrict__ stats, const float* __restrict__ instAcc,
                             const float* __restrict__ seediAcc, const float* __restrict__ seedbg,
                             float* __restrict__ out) {
  int b = threadIdx.x;
  __shared__ float red[64];
  float lb = 0.f;
  if (b < BATCH) {
    float sv = 0.f, si = 0.f, svar = 0.f, ssd = 0.f;
    for (int n = 0; n < NID; ++n) {
      Params pp = calc_params(stats + (size_t)(b * NID + n) * 8);
      float vf = pp.valid;
      sv += vf;
      si += vf * instAcc[b * NID + n];
      svar += vf * pp.var;
      ssd += vf * seediAcc[b * NID + n];
    }
    float obj = fmaxf(sv, 1.0f);
    lb = si / obj + 10.0f * (svar / obj) + (seedbg[b] + ssd) / (float)HW;
  }
  red[threadIdx.x] = lb;
  __syncthreads();
  for (int s = 32; s > 0; s >>= 1) {
    if (threadIdx.x < s) red[threadIdx.x] += red[threadIdx.x + s];
    __syncthreads();
  }
  if (threadIdx.x == 0) out[0] = red[0] / (float)BATCH;
}

extern "C" void kernel_launch(void* const* d_in, const int* in_sizes, int n_in,
                              void* d_out, int out_size, void* d_ws, size_t ws_size,
                              hipStream_t stream) {
  const float* pred = (const float*)d_in[0];
  const int* inst = (const int*)d_in[1];
  const int* lab = (const int*)d_in[2];
  float* out = (float*)d_out;

  // head (floats): seediAcc[240] | stats[1920] | instAcc[240] | seedbg[16]
  float* wsf = (float*)d_ws;
  float* seediAcc = wsf;
  float* stats = wsf + 240;
  float* instAcc = wsf + 2160;
  float* seedbg = wsf + 2400;
  char* p = (char*)d_ws + HEADB;
  unsigned* exyh = (unsigned*)p;            p += (size_t)BATCH * HW * 4;          // 16.78 MB
  unsigned* tb8 = (unsigned*)p;             p += (size_t)BATCH * HW;              // 4.19 MB
  unsigned* sd8 = (unsigned*)p;             p += (size_t)BATCH * HW;              // 4.19 MB
  unsigned* partPN = (unsigned*)p;          p += (size_t)NSEG * NSPL * KTOT * 4;  // 18.62 MB
  float* blockpart = (float*)p;             // 512*112*4 = 0.23 MB; total ~44.1 MB

  hipMemsetAsync(seediAcc, 0, 240 * sizeof(float), stream);
  pre_kernel<<<PREBLK, 256, 0, stream>>>(pred, inst, lab, blockpart, exyh, tb8, sd8, 0);
  pre_kernel<<<PREBLK, 256, 0, stream>>>(pred, inst, lab, blockpart, exyh, tb8, sd8, 8);
  reduce_kernel<<<dim3(NID * 7 + 1, BATCH), 64, 0, stream>>>(blockpart, stats, seedbg);
  hist_kernel<<<dim3(NSPL, NCHK, BATCH), 512, 0, stream>>>(exyh, tb8, sd8, stats, partPN, seediAcc);
  lovasz_kernel<<<NSEG, 1024, 0, stream>>>(partPN, stats, instAcc);
  final_kernel<<<1, 64, 0, stream>>>(stats, instAcc, seediAcc, seedbg, out);
}

// Round 9
// 252.657 us; speedup vs baseline: 1.0840x; 1.0840x over previous
//
#include <hip/hip_runtime.h>
#include <hip/hip_fp16.h>
#include <cmath>

#define BATCH 16
#define NID   15
#define NSEG  240
#define HW    262144          // 512*512
#define HEADB 65536
#define NSPL  8               // pixel splits per seg-chunk in hist
#define NCHK  2               // seg chunks (8+7) -- halves pixel re-reads vs 4 chunks
#define PREBLK 512            // pre blocks (32 per batch, 8192 px each)
#define PSTRIDE 112           // floats per pre-block partial record

// compact key space for d = exp(-arg) in [0,1]
#define KFINEBASE 30208       // 0x3B800000 >> 15
#define KOVF 119
#define KTOT 2424             // 119 + 2305

typedef float v2f __attribute__((ext_vector_type(2)));

__device__ __forceinline__ int keyof(float d) {
  unsigned b = __float_as_uint(d);
  return (b >= 0x3B800000u) ? (int)((b >> 15) - KFINEBASE + KOVF) : (int)(b >> 23);
}
__device__ __forceinline__ void boundsof(int k, float* lo, float* hi) {
  if (k >= KOVF) {
    unsigned u = (unsigned)(k - KOVF + KFINEBASE) << 15;
    *lo = __uint_as_float(u);
    *hi = __uint_as_float(u + 32768u);
  } else {
    *lo = __uint_as_float((unsigned)k << 23);
    *hi = __uint_as_float((unsigned)(k + 1) << 23);
  }
}

__device__ __forceinline__ float fast_tanh(float x) {
  float e = __expf(2.0f * x);
  return 1.0f - 2.0f / (e + 1.0f);
}
__device__ __forceinline__ float fast_sigmoid(float x) {
  return 1.0f / (1.0f + __expf(-x));
}

struct Params { float cx, cy, e0, e1, var, valid, cnt; };
__device__ __forceinline__ Params calc_params(const float* __restrict__ st) {
  Params p;
  float cnt = st[0];
  float safe = fmaxf(cnt, 1.0f);
  p.cx = st[1] / safe;
  p.cy = st[2] / safe;
  float m0 = st[3] / safe, m1 = st[4] / safe;
  float v0 = st[5] - 2.0f * m0 * (m0 * safe) + m0 * m0 * cnt;
  float v1 = st[6] - 2.0f * m1 * (m1 * safe) + m1 * m1 * cnt;
  p.var = (v0 + v1) / (2.0f * safe);
  p.e0 = expf(10.0f * m0);
  p.e1 = expf(10.0f * m1);
  p.valid = (cnt > 0.f) ? 1.f : 0.f;
  p.cnt = cnt;
  return p;
}

// ---------------- pre: register stats (R7-proven: single 512-block dispatch, 71us).
// __launch_bounds__(256,2) is MANDATORY (R4/R6: without it VGPR caps at 64 -> spill).
__global__ void __launch_bounds__(256, 2)
pre_kernel(const float* __restrict__ pred, const int* __restrict__ inst,
           const int* __restrict__ lab, float* __restrict__ blockpart,
           unsigned* __restrict__ exyh, unsigned* __restrict__ tb8,
           unsigned* __restrict__ sd8) {
  __shared__ float ws[4][NID * 7 + 1];
  int tid = threadIdx.x;
  int w = tid >> 6, lane = tid & 63;
  int gid = blockIdx.x;
  int b = gid >> 5, c = gid & 31;      // 32 blocks per batch, 8192 px per block
  const float* pb = pred + (size_t)b * 5 * HW;
  const int4* ip = (const int4*)(inst + (size_t)b * HW);
  const int4* lp = (const int4*)(lab + (size_t)b * HW);
  size_t bq = (size_t)b * (HW / 4);
  // acc pairs: [0]=(cnt,ex) [1]=(ey,p2) [2]=(p3,q2) [3]=(q3,-)
  v2f acc[NID][4];
#pragma unroll
  for (int id = 0; id < NID; ++id)
#pragma unroll
    for (int s = 0; s < 4; ++s) acc[id][s] = (v2f)(0.f);
  float bgacc = 0.f;
  // prologue prefetch of iteration 0
  int g0 = c * 2048 + tid;
  float4 A0 = ((const float4*)pb)[g0];
  float4 A1 = ((const float4*)(pb + HW))[g0];
  float4 A2 = ((const float4*)(pb + 2 * HW))[g0];
  float4 A3 = ((const float4*)(pb + 3 * HW))[g0];
  float4 A4 = ((const float4*)(pb + 4 * HW))[g0];
  int4 T4 = ip[g0];
  int4 L4 = lp[g0];
#pragma unroll 1
  for (int it = 0; it < 8; ++it) {
    int g = c * 2048 + it * 256 + tid;
    float4 v0 = A0, v1 = A1, v2 = A2, v3 = A3, v4 = A4;
    int4 t4 = T4, l4 = L4;
    if (it < 7) {
      int gn = g + 256;
      A0 = ((const float4*)pb)[gn];
      A1 = ((const float4*)(pb + HW))[gn];
      A2 = ((const float4*)(pb + 2 * HW))[gn];
      A3 = ((const float4*)(pb + 3 * HW))[gn];
      A4 = ((const float4*)(pb + 4 * HW))[gn];
      T4 = ip[gn];
      L4 = lp[gn];
    }
    float p0a[4] = {v0.x, v0.y, v0.z, v0.w};
    float p1a[4] = {v1.x, v1.y, v1.z, v1.w};
    float p2a[4] = {v2.x, v2.y, v2.z, v2.w};
    float p3a[4] = {v3.x, v3.y, v3.z, v3.w};
    float p4a[4] = {v4.x, v4.y, v4.z, v4.w};
    int ta[4] = {t4.x, t4.y, t4.z, t4.w};
    int la[4] = {l4.x, l4.y, l4.z, l4.w};
    unsigned eo[4], tpack = 0, spack = 0;
    int px0 = g * 4;
#pragma unroll
    for (int k = 0; k < 4; ++k) {
      int px = px0 + k;
      float xm = (float)(px & 511) * (1.0f / 511.0f);
      float ym = (float)(px >> 9) * (1.0f / 511.0f);
      float ex = fast_tanh(p0a[k]) + xm;
      float ey = fast_tanh(p1a[k]) + ym;
      float sd = fast_sigmoid(p4a[k]);
      __half2 h = __floats2half2_rn(ex, ey);
      eo[k] = *reinterpret_cast<unsigned*>(&h);
      int t = ta[k];
      tpack |= ((unsigned)(t & 255)) << (8 * k);
      unsigned sq = (unsigned)(sd * 255.0f + 0.5f);
      spack |= (sq & 255u) << (8 * k);
      float p2 = p2a[k], p3 = p3a[k];
      v2f P01; P01.x = 1.0f; P01.y = ex;
      v2f P23; P23.x = ey;   P23.y = p2;
      v2f P45; P45.x = p3;   P45.y = p2 * p2;
      v2f P67; P67.x = p3 * p3; P67.y = 0.f;
#pragma unroll
      for (int id = 0; id < NID; ++id) {
        float pr = (t == id + 1) ? 1.0f : 0.0f;
        v2f prv; prv.x = pr; prv.y = pr;
        acc[id][0] = prv * P01 + acc[id][0];
        acc[id][1] = prv * P23 + acc[id][1];
        acc[id][2] = prv * P45 + acc[id][2];
        acc[id][3] = prv * P67 + acc[id][3];
      }
      if (la[k] == 0) bgacc += sd * sd;
    }
    ((uint4*)exyh)[bq + g] = make_uint4(eo[0], eo[1], eo[2], eo[3]);
    tb8[bq + g] = tpack;
    sd8[bq + g] = spack;
  }
  // wave shfl reduction of 105 accumulators + bg
#pragma unroll
  for (int id = 0; id < NID; ++id) {
    float vals7[7] = {acc[id][0].x, acc[id][0].y, acc[id][1].x, acc[id][1].y,
                      acc[id][2].x, acc[id][2].y, acc[id][3].x};
#pragma unroll
    for (int s = 0; s < 7; ++s) {
      float v = vals7[s];
      for (int off = 32; off > 0; off >>= 1) v += __shfl_down(v, off, 64);
      if (lane == 0) ws[w][id * 7 + s] = v;
    }
  }
  for (int off = 32; off > 0; off >>= 1) bgacc += __shfl_down(bgacc, off, 64);
  if (lane == 0) ws[w][NID * 7] = bgacc;
  __syncthreads();
  float* bp = blockpart + (size_t)gid * PSTRIDE;
  for (int i = tid; i < NID * 7 + 1; i += 256)
    bp[i] = ws[0][i] + ws[1][i] + ws[2][i] + ws[3][i];
}

// ---------------- reduce pre partials (32 blocks/batch) -> stats, seedbg ----------------
__global__ void reduce_kernel(const float* __restrict__ blockpart, float* __restrict__ stats,
                              float* __restrict__ seedbg) {
  int s = blockIdx.x;       // 0..105
  int b = blockIdx.y;
  int tid = threadIdx.x;    // 64
  float v = (tid < 32) ? blockpart[(size_t)(b * 32 + tid) * PSTRIDE + s] : 0.f;
  for (int off = 32; off > 0; off >>= 1) v += __shfl_down(v, off, 64);
  if (tid == 0) {
    if (s < NID * 7) {
      int id = s / 7, st = s % 7;
      stats[(b * NID + id) * 8 + st] = v;
    } else {
      seedbg[b] = v;
    }
  }
}

// ---------------- hist: 8 segments per block (2 chunks), packed pos|neg LDS histograms.
// NCHK 4->2 halves the re-read of the 25MB packed-pixel intermediate (100->50 MB).
__global__ void __launch_bounds__(512)
hist_kernel(const unsigned* __restrict__ exyh, const unsigned* __restrict__ tb8,
            const unsigned* __restrict__ sd8, const float* __restrict__ stats,
            unsigned* __restrict__ partPN, float* __restrict__ seedi) {
  int split = blockIdx.x;       // 0..7
  int chunk = blockIdx.y;       // 0..1
  int b = blockIdx.z;           // 0..15
  int seg0 = chunk * 8;         // first seg id in chunk (8 segs; chunk1 has 7 valid)
  __shared__ unsigned lhist[8 * KTOT];   // 77.6 KB (gfx950 allows >64KB static LDS)
  __shared__ float prm[8][5];   // cx, cy, e0, e1, valid
  int tid = threadIdx.x;
  if (tid < 8) {
    int gs = seg0 + tid;
    if (gs < NID) {
      Params pp = calc_params(stats + (size_t)(b * NID + gs) * 8);
      prm[tid][0] = pp.cx; prm[tid][1] = pp.cy; prm[tid][2] = pp.e0; prm[tid][3] = pp.e1;
      prm[tid][4] = pp.valid;
    } else {
      prm[tid][4] = 0.f;
    }
  }
  for (int k = tid; k < 8 * KTOT; k += 512) lhist[k] = 0u;
  __syncthreads();
  float cxr[8], cyr[8], e0r[8], e1r[8];
  bool vr[8];
#pragma unroll
  for (int n = 0; n < 8; ++n) {
    cxr[n] = prm[n][0]; cyr[n] = prm[n][1]; e0r[n] = prm[n][2]; e1r[n] = prm[n][3];
    vr[n] = (prm[n][4] != 0.f);
  }
  const uint4* ev = (const uint4*)exyh + (size_t)b * (HW / 4);
  const unsigned* tv = tb8 + (size_t)b * (HW / 4);
  const unsigned* sv = sd8 + (size_t)b * (HW / 4);
  int lane = tid & 63;
  int wid = tid >> 6;               // 8 waves
  int swl = (lane * 21) & 63;       // decorrelate bucket keys within a wave
  float sacc[8] = {0.f, 0.f, 0.f, 0.f, 0.f, 0.f, 0.f, 0.f};
  // groups: 65536/batch; per split 8192; per block 16 iters of 512
  int g = split * 8192 + wid * 64 + swl;
  uint4 ee = ev[g];
  unsigned tp = tv[g];
  unsigned sp = sv[g];
  for (int it = 0; it < 16; ++it) {
    uint4 ne; unsigned ntp, nsp;
    int ng = g + 512;
    if (it < 15) { ne = ev[ng]; ntp = tv[ng]; nsp = sv[ng]; }
    unsigned ew[4] = {ee.x, ee.y, ee.z, ee.w};
#pragma unroll
    for (int k = 0; k < 4; ++k) {
      unsigned u = ew[k];
      __half2 h = *reinterpret_cast<__half2*>(&u);
      float2 e = __half22float2(h);
      int t = (int)((tp >> (8 * k)) & 255u);
#pragma unroll
      for (int n = 0; n < 8; ++n) {
        if (!vr[n]) continue;
        float dx = e.x - cxr[n];
        float dy = e.y - cyr[n];
        float d = __expf(-(e0r[n] * dx * dx + e1r[n] * dy * dy));
        int key = keyof(d);
        bool pos = (t == seg0 + n + 1);
        atomicAdd(&lhist[n * KTOT + key], pos ? 65536u : 1u);
        if (pos) {
          float sd = (float)((sp >> (8 * k)) & 255u) * (1.0f / 255.0f);
          float df = sd - d;
          sacc[n] += df * df;
        }
      }
    }
    if (it < 15) { ee = ne; tp = ntp; sp = nsp; g = ng; }
  }
#pragma unroll
  for (int n = 0; n < 8; ++n) {
    float v = sacc[n];
    for (int off = 32; off > 0; off >>= 1) v += __shfl_down(v, off, 64);
    if (lane == 0 && v != 0.f) atomicAdd(&seedi[b * NID + seg0 + n], v);
  }
  __syncthreads();
#pragma unroll
  for (int n = 0; n < 8; ++n) {
    int gs = seg0 + n;
    if (gs >= NID) break;
    size_t base = ((size_t)(b * NID + gs) * NSPL + split) * KTOT;
    for (int k = tid; k < KTOT; k += 512) partPN[base + k] = lhist[n * KTOT + k];
  }
}

// ---------------- lovasz: barrier-light wave-shfl scans ----------------
__global__ void __launch_bounds__(1024)
lovasz_kernel(const unsigned* __restrict__ partPN, const float* __restrict__ stats,
              float* __restrict__ instAcc) {
  __shared__ int histP[KTOT];
  __shared__ int histN[KTOT];
  __shared__ int PreP[KTOT + 1];
  __shared__ int PreN[KTOT + 1];
  __shared__ int wtP[16];
  __shared__ int wtN[16];
  __shared__ float wred[16];
  __shared__ float prm[2];
  int seg = blockIdx.x;
  int tid = threadIdx.x;
  int lane = tid & 63, w = tid >> 6;
  if (tid == 0) {
    Params pp = calc_params(stats + (size_t)seg * 8);
    prm[0] = pp.valid;
    prm[1] = pp.cnt;
  }
  __syncthreads();
  if (prm[0] == 0.f) {
    if (tid == 0) instAcc[seg] = 0.f;
    return;
  }
  int P = (int)prm[1];
  int Nn = HW - P;
  for (int k = tid; k < KTOT; k += 1024) {
    int sp = 0, sn = 0;
#pragma unroll
    for (int s = 0; s < NSPL; ++s) {
      unsigned v = partPN[((size_t)seg * NSPL + s) * KTOT + k];
      sp += (int)(v >> 16);
      sn += (int)(v & 0xFFFFu);
    }
    histP[k] = sp;
    histN[k] = sn;
  }
  __syncthreads();
  // --- prefix sums of histP/histN via wave shfl scans ---
  {
    int base = tid * 3;
    int p0 = (base < KTOT) ? histP[base] : 0;
    int p1 = (base + 1 < KTOT) ? histP[base + 1] : 0;
    int p2 = (base + 2 < KTOT) ? histP[base + 2] : 0;
    int n0 = (base < KTOT) ? histN[base] : 0;
    int n1 = (base + 1 < KTOT) ? histN[base + 1] : 0;
    int n2 = (base + 2 < KTOT) ? histN[base + 2] : 0;
    int ap = p0 + p1 + p2, an = n0 + n1 + n2;
    int sip = ap, sin_ = an;          // wave-inclusive scans
    for (int off = 1; off < 64; off <<= 1) {
      int up = __shfl_up(sip, off, 64);
      int un = __shfl_up(sin_, off, 64);
      if (lane >= off) { sip += up; sin_ += un; }
    }
    if (lane == 63) { wtP[w] = sip; wtN[w] = sin_; }
    __syncthreads();
    int woffP = 0, woffN = 0, totP = 0, totN = 0;
#pragma unroll
    for (int j = 0; j < 16; ++j) {
      int tp = wtP[j], tn = wtN[j];
      totP += tp; totN += tn;
      if (j < w) { woffP += tp; woffN += tn; }
    }
    int exP = woffP + sip - ap;       // exclusive prefix over all earlier threads
    int exN = woffN + sin_ - an;
    if (base < KTOT) {
      PreP[base] = exP;
      PreN[base] = exN;
    }
    if (base + 1 < KTOT) {
      PreP[base + 1] = exP + p0;
      PreN[base + 1] = exN + n0;
    }
    if (base + 2 < KTOT) {
      PreP[base + 2] = exP + p0 + p1;
      PreN[base + 2] = exN + n0 + n1;
    }
    if (tid == 0) {
      PreP[KTOT] = totP;
      PreN[KTOT] = totN;
    }
    __syncthreads();
  }
  float acc = 0.f;
  for (int k = tid; k < KTOT; k += 1024) {
    int hp = histP[k], hn = histN[k];
    if ((hp | hn) == 0) continue;
    float lo, hi;
    boundsof(k, &lo, &hi);
    float m = 0.5f * (lo + hi);
    m = fminf(m, __uint_as_float(0x3F7FFFFFu));
    float tv = 1.0f - m;
    int j = keyof(tv);
    float jlo, jhi;
    boundsof(j, &jlo, &jhi);
    float den = jhi - jlo;
    float fr = (den > 0.f) ? (tv - jlo) / den : 0.5f;
    fr = fminf(fmaxf(fr, 0.f), 1.f);
    if (hp) {
      float q = (float)(Nn - PreN[j + 1]) + (1.0f - fr) * (float)histN[j];
      float a = 2.0f - 2.0f * m;
      acc += (float)hp * a / ((float)P + q);
    }
    if (hn) {
      float p = (float)PreP[j] + fr * (float)histP[j];
      int R = Nn - PreN[k + 1];
      float u0 = 1.0f / (float)(P + R);
      float u1 = 1.0f / (float)(P + R + hn);
      acc += (2.0f * m) * ((float)P - p) * (u0 - u1);
    }
  }
  // block reduction: wave shfl + 16 partials + wave-0 finish
  for (int off = 32; off > 0; off >>= 1) acc += __shfl_down(acc, off, 64);
  if (lane == 0) wred[w] = acc;
  __syncthreads();
  if (w == 0) {
    float v = (lane < 16) ? wred[lane] : 0.f;
    for (int off = 8; off > 0; off >>= 1) v += __shfl_down(v, off, 64);
    if (lane == 0) instAcc[seg] = v;
  }
}

// ---------------- final combine ----------------
__global__ void final_kernel(const float* __restrict__ stats, const float* __restrict__ instAcc,
                             const float* __restrict__ seediAcc, const float* __restrict__ seedbg,
                             float* __restrict__ out) {
  int b = threadIdx.x;
  __shared__ float red[64];
  float lb = 0.f;
  if (b < BATCH) {
    float sv = 0.f, si = 0.f, svar = 0.f, ssd = 0.f;
    for (int n = 0; n < NID; ++n) {
      Params pp = calc_params(stats + (size_t)(b * NID + n) * 8);
      float vf = pp.valid;
      sv += vf;
      si += vf * instAcc[b * NID + n];
      svar += vf * pp.var;
      ssd += vf * seediAcc[b * NID + n];
    }
    float obj = fmaxf(sv, 1.0f);
    lb = si / obj + 10.0f * (svar / obj) + (seedbg[b] + ssd) / (float)HW;
  }
  red[threadIdx.x] = lb;
  __syncthreads();
  for (int s = 32; s > 0; s >>= 1) {
    if (threadIdx.x < s) red[threadIdx.x] += red[threadIdx.x + s];
    __syncthreads();
  }
  if (threadIdx.x == 0) out[0] = red[0] / (float)BATCH;
}

extern "C" void kernel_launch(void* const* d_in, const int* in_sizes, int n_in,
                              void* d_out, int out_size, void* d_ws, size_t ws_size,
                              hipStream_t stream) {
  const float* pred = (const float*)d_in[0];
  const int* inst = (const int*)d_in[1];
  const int* lab = (const int*)d_in[2];
  float* out = (float*)d_out;

  // head (floats): seediAcc[240] | stats[1920] | instAcc[240] | seedbg[16]
  float* wsf = (float*)d_ws;
  float* seediAcc = wsf;
  float* stats = wsf + 240;
  float* instAcc = wsf + 2160;
  float* seedbg = wsf + 2400;
  char* p = (char*)d_ws + HEADB;
  unsigned* exyh = (unsigned*)p;            p += (size_t)BATCH * HW * 4;          // 16.78 MB
  unsigned* tb8 = (unsigned*)p;             p += (size_t)BATCH * HW;              // 4.19 MB
  unsigned* sd8 = (unsigned*)p;             p += (size_t)BATCH * HW;              // 4.19 MB
  unsigned* partPN = (unsigned*)p;          p += (size_t)NSEG * NSPL * KTOT * 4;  // 18.62 MB
  float* blockpart = (float*)p;             // 512*112*4 = 0.23 MB; total ~44.1 MB

  hipMemsetAsync(seediAcc, 0, 240 * sizeof(float), stream);
  pre_kernel<<<PREBLK, 256, 0, stream>>>(pred, inst, lab, blockpart, exyh, tb8, sd8);
  reduce_kernel<<<dim3(NID * 7 + 1, BATCH), 64, 0, stream>>>(blockpart, stats, seedbg);
  hist_kernel<<<dim3(NSPL, NCHK, BATCH), 512, 0, stream>>>(exyh, tb8, sd8, stats, partPN, seediAcc);
  lovasz_kernel<<<NSEG, 1024, 0, stream>>>(partPN, stats, instAcc);
  final_kernel<<<1, 64, 0, stream>>>(stats, instAcc, seediAcc, seedbg, out);
}

// Round 10
// 250.966 us; speedup vs baseline: 1.0913x; 1.0067x over previous
//
#include <hip/hip_runtime.h>
#include <hip/hip_fp16.h>
#include <cmath>

#define BATCH 16
#define NID   15
#define NSEG  240
#define HW    262144          // 512*512
#define HEADB 65536
#define NSPL  8               // pixel splits per seg-chunk in hist
#define PREBLK 512            // pre blocks (32 per batch, 8192 px each)
#define PSTRIDE 112           // floats per pre-block partial record

// compact key space for d = exp(-arg) in [0,1]
#define KFINEBASE 30208       // 0x3B800000 >> 15
#define KOVF 119
#define KTOT 2424             // 119 + 2305

typedef float v2f __attribute__((ext_vector_type(2)));

__device__ __forceinline__ int keyof(float d) {
  unsigned b = __float_as_uint(d);
  return (b >= 0x3B800000u) ? (int)((b >> 15) - KFINEBASE + KOVF) : (int)(b >> 23);
}
__device__ __forceinline__ void boundsof(int k, float* lo, float* hi) {
  if (k >= KOVF) {
    unsigned u = (unsigned)(k - KOVF + KFINEBASE) << 15;
    *lo = __uint_as_float(u);
    *hi = __uint_as_float(u + 32768u);
  } else {
    *lo = __uint_as_float((unsigned)k << 23);
    *hi = __uint_as_float((unsigned)(k + 1) << 23);
  }
}

__device__ __forceinline__ float fast_tanh(float x) {
  float e = __expf(2.0f * x);
  return 1.0f - 2.0f / (e + 1.0f);
}
__device__ __forceinline__ float fast_sigmoid(float x) {
  return 1.0f / (1.0f + __expf(-x));
}

struct Params { float cx, cy, e0, e1, var, valid, cnt; };
__device__ __forceinline__ Params calc_params(const float* __restrict__ st) {
  Params p;
  float cnt = st[0];
  float safe = fmaxf(cnt, 1.0f);
  p.cx = st[1] / safe;
  p.cy = st[2] / safe;
  float m0 = st[3] / safe, m1 = st[4] / safe;
  float v0 = st[5] - 2.0f * m0 * (m0 * safe) + m0 * m0 * cnt;
  float v1 = st[6] - 2.0f * m1 * (m1 * safe) + m1 * m1 * cnt;
  p.var = (v0 + v1) / (2.0f * safe);
  p.e0 = expf(10.0f * m0);
  p.e1 = expf(10.0f * m1);
  p.valid = (cnt > 0.f) ? 1.f : 0.f;
  p.cnt = cnt;
  return p;
}

// sum the 32 per-block partials for (batch b, stat slot i) -- replaces reduce_kernel
__device__ __forceinline__ float sum_partials(const float* __restrict__ blockpart,
                                              int b, int slot) {
  const float* bp = blockpart + (size_t)(b * 32) * PSTRIDE + slot;
  float v = 0.f;
#pragma unroll
  for (int i = 0; i < 32; ++i) v += bp[(size_t)i * PSTRIDE];
  return v;
}

// ---------------- pre: register stats (R7-proven: 512x256, 72us). Block 0 also
// zeroes seediAcc (replaces the memset dispatch; hist runs strictly after pre).
// __launch_bounds__(256,2) is MANDATORY (R4/R6: without it VGPR caps at 64 -> spill).
__global__ void __launch_bounds__(256, 2)
pre_kernel(const float* __restrict__ pred, const int* __restrict__ inst,
           const int* __restrict__ lab, float* __restrict__ blockpart,
           unsigned* __restrict__ exyh, unsigned* __restrict__ tb8,
           unsigned* __restrict__ sd8, float* __restrict__ seediAcc) {
  __shared__ float ws[4][NID * 7 + 1];
  int tid = threadIdx.x;
  int w = tid >> 6, lane = tid & 63;
  int gid = blockIdx.x;
  if (gid == 0) {
    for (int i = tid; i < NSEG; i += 256) seediAcc[i] = 0.f;
  }
  int b = gid >> 5, c = gid & 31;      // 32 blocks per batch, 8192 px per block
  const float* pb = pred + (size_t)b * 5 * HW;
  const int4* ip = (const int4*)(inst + (size_t)b * HW);
  const int4* lp = (const int4*)(lab + (size_t)b * HW);
  size_t bq = (size_t)b * (HW / 4);
  // acc pairs: [0]=(cnt,ex) [1]=(ey,p2) [2]=(p3,q2) [3]=(q3,-)
  v2f acc[NID][4];
#pragma unroll
  for (int id = 0; id < NID; ++id)
#pragma unroll
    for (int s = 0; s < 4; ++s) acc[id][s] = (v2f)(0.f);
  float bgacc = 0.f;
  // prologue prefetch of iteration 0
  int g0 = c * 2048 + tid;
  float4 A0 = ((const float4*)pb)[g0];
  float4 A1 = ((const float4*)(pb + HW))[g0];
  float4 A2 = ((const float4*)(pb + 2 * HW))[g0];
  float4 A3 = ((const float4*)(pb + 3 * HW))[g0];
  float4 A4 = ((const float4*)(pb + 4 * HW))[g0];
  int4 T4 = ip[g0];
  int4 L4 = lp[g0];
#pragma unroll 1
  for (int it = 0; it < 8; ++it) {
    int g = c * 2048 + it * 256 + tid;
    float4 v0 = A0, v1 = A1, v2 = A2, v3 = A3, v4 = A4;
    int4 t4 = T4, l4 = L4;
    if (it < 7) {
      int gn = g + 256;
      A0 = ((const float4*)pb)[gn];
      A1 = ((const float4*)(pb + HW))[gn];
      A2 = ((const float4*)(pb + 2 * HW))[gn];
      A3 = ((const float4*)(pb + 3 * HW))[gn];
      A4 = ((const float4*)(pb + 4 * HW))[gn];
      T4 = ip[gn];
      L4 = lp[gn];
    }
    float p0a[4] = {v0.x, v0.y, v0.z, v0.w};
    float p1a[4] = {v1.x, v1.y, v1.z, v1.w};
    float p2a[4] = {v2.x, v2.y, v2.z, v2.w};
    float p3a[4] = {v3.x, v3.y, v3.z, v3.w};
    float p4a[4] = {v4.x, v4.y, v4.z, v4.w};
    int ta[4] = {t4.x, t4.y, t4.z, t4.w};
    int la[4] = {l4.x, l4.y, l4.z, l4.w};
    unsigned eo[4], tpack = 0, spack = 0;
    int px0 = g * 4;
#pragma unroll
    for (int k = 0; k < 4; ++k) {
      int px = px0 + k;
      float xm = (float)(px & 511) * (1.0f / 511.0f);
      float ym = (float)(px >> 9) * (1.0f / 511.0f);
      float ex = fast_tanh(p0a[k]) + xm;
      float ey = fast_tanh(p1a[k]) + ym;
      float sd = fast_sigmoid(p4a[k]);
      __half2 h = __floats2half2_rn(ex, ey);
      eo[k] = *reinterpret_cast<unsigned*>(&h);
      int t = ta[k];
      tpack |= ((unsigned)(t & 255)) << (8 * k);
      unsigned sq = (unsigned)(sd * 255.0f + 0.5f);
      spack |= (sq & 255u) << (8 * k);
      float p2 = p2a[k], p3 = p3a[k];
      v2f P01; P01.x = 1.0f; P01.y = ex;
      v2f P23; P23.x = ey;   P23.y = p2;
      v2f P45; P45.x = p3;   P45.y = p2 * p2;
      v2f P67; P67.x = p3 * p3; P67.y = 0.f;
#pragma unroll
      for (int id = 0; id < NID; ++id) {
        float pr = (t == id + 1) ? 1.0f : 0.0f;
        v2f prv; prv.x = pr; prv.y = pr;
        acc[id][0] = prv * P01 + acc[id][0];
        acc[id][1] = prv * P23 + acc[id][1];
        acc[id][2] = prv * P45 + acc[id][2];
        acc[id][3] = prv * P67 + acc[id][3];
      }
      if (la[k] == 0) bgacc += sd * sd;
    }
    ((uint4*)exyh)[bq + g] = make_uint4(eo[0], eo[1], eo[2], eo[3]);
    tb8[bq + g] = tpack;
    sd8[bq + g] = spack;
  }
  // wave shfl reduction of 105 accumulators + bg
#pragma unroll
  for (int id = 0; id < NID; ++id) {
    float vals7[7] = {acc[id][0].x, acc[id][0].y, acc[id][1].x, acc[id][1].y,
                      acc[id][2].x, acc[id][2].y, acc[id][3].x};
#pragma unroll
    for (int s = 0; s < 7; ++s) {
      float v = vals7[s];
      for (int off = 32; off > 0; off >>= 1) v += __shfl_down(v, off, 64);
      if (lane == 0) ws[w][id * 7 + s] = v;
    }
  }
  for (int off = 32; off > 0; off >>= 1) bgacc += __shfl_down(bgacc, off, 64);
  if (lane == 0) ws[w][NID * 7] = bgacc;
  __syncthreads();
  float* bp = blockpart + (size_t)gid * PSTRIDE;
  for (int i = tid; i < NID * 7 + 1; i += 256)
    bp[i] = ws[0][i] + ws[1][i] + ws[2][i] + ws[3][i];
}

// ---------------- hist: 4 segments per block, inline stats from blockpart.
// Launched TWICE (cpair=0,1), 256 blocks each (full chip) for counter visibility.
__global__ void __launch_bounds__(512)
hist_kernel(const unsigned* __restrict__ exyh, const unsigned* __restrict__ tb8,
            const unsigned* __restrict__ sd8, const float* __restrict__ blockpart,
            unsigned* __restrict__ partPN, float* __restrict__ seedi, int cpair) {
  int split = blockIdx.x;       // 0..7
  int chunk = cpair * 2 + blockIdx.y;   // 0..3
  int b = blockIdx.z;           // 0..15
  int seg0 = chunk * 4;         // first seg id in chunk (seg0..seg0+3, <15)
  __shared__ unsigned lhist[4 * KTOT];
  __shared__ float st8[4][8];   // inline per-seg stat sums (7 used)
  __shared__ float prm[4][5];   // cx, cy, e0, e1, valid
  int tid = threadIdx.x;
  if (tid < 28) {
    int n = tid / 7, s = tid - n * 7;
    int gs = seg0 + n;
    float v = 0.f;
    if (gs < NID) v = sum_partials(blockpart, b, gs * 7 + s);
    st8[n][s] = v;
  }
  for (int k = tid; k < 4 * KTOT; k += 512) lhist[k] = 0u;
  __syncthreads();
  if (tid < 4) {
    int gs = seg0 + tid;
    if (gs < NID) {
      Params pp = calc_params(st8[tid]);
      prm[tid][0] = pp.cx; prm[tid][1] = pp.cy; prm[tid][2] = pp.e0; prm[tid][3] = pp.e1;
      prm[tid][4] = pp.valid;
    } else {
      prm[tid][4] = 0.f;
    }
  }
  __syncthreads();
  float cxr[4], cyr[4], e0r[4], e1r[4];
  bool vr[4];
#pragma unroll
  for (int n = 0; n < 4; ++n) {
    cxr[n] = prm[n][0]; cyr[n] = prm[n][1]; e0r[n] = prm[n][2]; e1r[n] = prm[n][3];
    vr[n] = (prm[n][4] != 0.f);
  }
  const uint4* ev = (const uint4*)exyh + (size_t)b * (HW / 4);
  const unsigned* tv = tb8 + (size_t)b * (HW / 4);
  const unsigned* sv = sd8 + (size_t)b * (HW / 4);
  int lane = tid & 63;
  int wid = tid >> 6;               // 8 waves
  int swl = (lane * 21) & 63;       // decorrelate bucket keys within a wave
  float sacc[4] = {0.f, 0.f, 0.f, 0.f};
  // groups: 65536/batch; per split 8192; per block 16 iters of 512
  int g = split * 8192 + wid * 64 + swl;
  uint4 ee = ev[g];
  unsigned tp = tv[g];
  unsigned sp = sv[g];
  for (int it = 0; it < 16; ++it) {
    uint4 ne; unsigned ntp, nsp;
    int ng = g + 512;
    if (it < 15) { ne = ev[ng]; ntp = tv[ng]; nsp = sv[ng]; }
    unsigned ew[4] = {ee.x, ee.y, ee.z, ee.w};
#pragma unroll
    for (int k = 0; k < 4; ++k) {
      unsigned u = ew[k];
      __half2 h = *reinterpret_cast<__half2*>(&u);
      float2 e = __half22float2(h);
      int t = (int)((tp >> (8 * k)) & 255u);
#pragma unroll
      for (int n = 0; n < 4; ++n) {
        if (!vr[n]) continue;
        float dx = e.x - cxr[n];
        float dy = e.y - cyr[n];
        float d = __expf(-(e0r[n] * dx * dx + e1r[n] * dy * dy));
        int key = keyof(d);
        bool pos = (t == seg0 + n + 1);
        atomicAdd(&lhist[n * KTOT + key], pos ? 65536u : 1u);
        if (pos) {
          float sd = (float)((sp >> (8 * k)) & 255u) * (1.0f / 255.0f);
          float df = sd - d;
          sacc[n] += df * df;
        }
      }
    }
    if (it < 15) { ee = ne; tp = ntp; sp = nsp; g = ng; }
  }
#pragma unroll
  for (int n = 0; n < 4; ++n) {
    float v = sacc[n];
    for (int off = 32; off > 0; off >>= 1) v += __shfl_down(v, off, 64);
    if (lane == 0 && v != 0.f) atomicAdd(&seedi[b * NID + seg0 + n], v);
  }
  __syncthreads();
#pragma unroll
  for (int n = 0; n < 4; ++n) {
    int gs = seg0 + n;
    if (gs >= NID) break;
    size_t base = ((size_t)(b * NID + gs) * NSPL + split) * KTOT;
    for (int k = tid; k < KTOT; k += 512) partPN[base + k] = lhist[n * KTOT + k];
  }
}

// ---------------- lovasz: inline stats; emits instAcc + {valid,var} per seg ----------------
__global__ void __launch_bounds__(1024)
lovasz_kernel(const unsigned* __restrict__ partPN, const float* __restrict__ blockpart,
              float* __restrict__ instAcc, float2* __restrict__ varv) {
  __shared__ int histP[KTOT];
  __shared__ int histN[KTOT];
  __shared__ int PreP[KTOT + 1];
  __shared__ int PreN[KTOT + 1];
  __shared__ int wtP[16];
  __shared__ int wtN[16];
  __shared__ float wred[16];
  __shared__ float st[8];
  __shared__ float prm[2];
  int seg = blockIdx.x;
  int tid = threadIdx.x;
  int lane = tid & 63, w = tid >> 6;
  int sb = seg / NID, sn = seg - sb * NID;
  if (tid < 7) st[tid] = sum_partials(blockpart, sb, sn * 7 + tid);
  __syncthreads();
  if (tid == 0) {
    Params pp = calc_params(st);
    prm[0] = pp.valid;
    prm[1] = pp.cnt;
    varv[seg] = make_float2(pp.valid, pp.var);
  }
  __syncthreads();
  if (prm[0] == 0.f) {
    if (tid == 0) instAcc[seg] = 0.f;
    return;
  }
  int P = (int)prm[1];
  int Nn = HW - P;
  for (int k = tid; k < KTOT; k += 1024) {
    int sp = 0, sn2 = 0;
#pragma unroll
    for (int s = 0; s < NSPL; ++s) {
      unsigned v = partPN[((size_t)seg * NSPL + s) * KTOT + k];
      sp += (int)(v >> 16);
      sn2 += (int)(v & 0xFFFFu);
    }
    histP[k] = sp;
    histN[k] = sn2;
  }
  __syncthreads();
  // --- prefix sums of histP/histN via wave shfl scans ---
  {
    int base = tid * 3;
    int p0 = (base < KTOT) ? histP[base] : 0;
    int p1 = (base + 1 < KTOT) ? histP[base + 1] : 0;
    int p2 = (base + 2 < KTOT) ? histP[base + 2] : 0;
    int n0 = (base < KTOT) ? histN[base] : 0;
    int n1 = (base + 1 < KTOT) ? histN[base + 1] : 0;
    int n2 = (base + 2 < KTOT) ? histN[base + 2] : 0;
    int ap = p0 + p1 + p2, an = n0 + n1 + n2;
    int sip = ap, sin_ = an;          // wave-inclusive scans
    for (int off = 1; off < 64; off <<= 1) {
      int up = __shfl_up(sip, off, 64);
      int un = __shfl_up(sin_, off, 64);
      if (lane >= off) { sip += up; sin_ += un; }
    }
    if (lane == 63) { wtP[w] = sip; wtN[w] = sin_; }
    __syncthreads();
    int woffP = 0, woffN = 0, totP = 0, totN = 0;
#pragma unroll
    for (int j = 0; j < 16; ++j) {
      int tp = wtP[j], tn = wtN[j];
      totP += tp; totN += tn;
      if (j < w) { woffP += tp; woffN += tn; }
    }
    int exP = woffP + sip - ap;       // exclusive prefix over all earlier threads
    int exN = woffN + sin_ - an;
    if (base < KTOT) {
      PreP[base] = exP;
      PreN[base] = exN;
    }
    if (base + 1 < KTOT) {
      PreP[base + 1] = exP + p0;
      PreN[base + 1] = exN + n0;
    }
    if (base + 2 < KTOT) {
      PreP[base + 2] = exP + p0 + p1;
      PreN[base + 2] = exN + n0 + n1;
    }
    if (tid == 0) {
      PreP[KTOT] = totP;
      PreN[KTOT] = totN;
    }
    __syncthreads();
  }
  float acc = 0.f;
  for (int k = tid; k < KTOT; k += 1024) {
    int hp = histP[k], hn = histN[k];
    if ((hp | hn) == 0) continue;
    float lo, hi;
    boundsof(k, &lo, &hi);
    float m = 0.5f * (lo + hi);
    m = fminf(m, __uint_as_float(0x3F7FFFFFu));
    float tv = 1.0f - m;
    int j = keyof(tv);
    float jlo, jhi;
    boundsof(j, &jlo, &jhi);
    float den = jhi - jlo;
    float fr = (den > 0.f) ? (tv - jlo) / den : 0.5f;
    fr = fminf(fmaxf(fr, 0.f), 1.f);
    if (hp) {
      float q = (float)(Nn - PreN[j + 1]) + (1.0f - fr) * (float)histN[j];
      float a = 2.0f - 2.0f * m;
      acc += (float)hp * a / ((float)P + q);
    }
    if (hn) {
      float p = (float)PreP[j] + fr * (float)histP[j];
      int R = Nn - PreN[k + 1];
      float u0 = 1.0f / (float)(P + R);
      float u1 = 1.0f / (float)(P + R + hn);
      acc += (2.0f * m) * ((float)P - p) * (u0 - u1);
    }
  }
  // block reduction: wave shfl + 16 partials + wave-0 finish
  for (int off = 32; off > 0; off >>= 1) acc += __shfl_down(acc, off, 64);
  if (lane == 0) wred[w] = acc;
  __syncthreads();
  if (w == 0) {
    float v = (lane < 16) ? wred[lane] : 0.f;
    for (int off = 8; off > 0; off >>= 1) v += __shfl_down(v, off, 64);
    if (lane == 0) instAcc[seg] = v;
  }
}

// ---------------- final combine (seedbg computed inline from blockpart) ----------------
__global__ void final_kernel(const float* __restrict__ instAcc, const float2* __restrict__ varv,
                             const float* __restrict__ seediAcc,
                             const float* __restrict__ blockpart, float* __restrict__ out) {
  int b = threadIdx.x;
  __shared__ float red[64];
  float lb = 0.f;
  if (b < BATCH) {
    float seedbg = sum_partials(blockpart, b, NID * 7);
    float sv = 0.f, si = 0.f, svar = 0.f, ssd = 0.f;
    for (int n = 0; n < NID; ++n) {
      float2 vv = varv[b * NID + n];
      sv += vv.x;
      si += vv.x * instAcc[b * NID + n];
      svar += vv.x * vv.y;
      ssd += vv.x * seediAcc[b * NID + n];
    }
    float obj = fmaxf(sv, 1.0f);
    lb = si / obj + 10.0f * (svar / obj) + (seedbg + ssd) / (float)HW;
  }
  red[threadIdx.x] = lb;
  __syncthreads();
  for (int s = 32; s > 0; s >>= 1) {
    if (threadIdx.x < s) red[threadIdx.x] += red[threadIdx.x + s];
    __syncthreads();
  }
  if (threadIdx.x == 0) out[0] = red[0] / (float)BATCH;
}

extern "C" void kernel_launch(void* const* d_in, const int* in_sizes, int n_in,
                              void* d_out, int out_size, void* d_ws, size_t ws_size,
                              hipStream_t stream) {
  const float* pred = (const float*)d_in[0];
  const int* inst = (const int*)d_in[1];
  const int* lab = (const int*)d_in[2];
  float* out = (float*)d_out;

  // head (floats): seediAcc[240] | varv[480] | instAcc[240] (at +2160)
  float* wsf = (float*)d_ws;
  float* seediAcc = wsf;
  float2* varv = (float2*)(wsf + 240);
  float* instAcc = wsf + 2160;
  char* p = (char*)d_ws + HEADB;
  unsigned* exyh = (unsigned*)p;            p += (size_t)BATCH * HW * 4;          // 16.78 MB
  unsigned* tb8 = (unsigned*)p;             p += (size_t)BATCH * HW;              // 4.19 MB
  unsigned* sd8 = (unsigned*)p;             p += (size_t)BATCH * HW;              // 4.19 MB
  unsigned* partPN = (unsigned*)p;          p += (size_t)NSEG * NSPL * KTOT * 4;  // 18.62 MB
  float* blockpart = (float*)p;             // 512*112*4 = 0.23 MB; total ~44.1 MB

  pre_kernel<<<PREBLK, 256, 0, stream>>>(pred, inst, lab, blockpart, exyh, tb8, sd8, seediAcc);
  hist_kernel<<<dim3(NSPL, 2, BATCH), 512, 0, stream>>>(exyh, tb8, sd8, blockpart, partPN, seediAcc, 0);
  hist_kernel<<<dim3(NSPL, 2, BATCH), 512, 0, stream>>>(exyh, tb8, sd8, blockpart, partPN, seediAcc, 1);
  lovasz_kernel<<<NSEG, 1024, 0, stream>>>(partPN, blockpart, instAcc, varv);
  final_kernel<<<1, 64, 0, stream>>>(instAcc, varv, seediAcc, blockpart, out);
}